// Round 3
// baseline (312.203 us; speedup 1.0000x reference)
//
#include <hip/hip_runtime.h>
#include <hip/hip_bf16.h>
#include <cmath>

typedef __bf16 bf16_t;
typedef __bf16 bf16x8 __attribute__((ext_vector_type(8)));
typedef float f32x4 __attribute__((ext_vector_type(4)));

#define MFMA16(A, B, C) __builtin_amdgcn_mfma_f32_16x16x32_bf16(A, B, C, 0, 0, 0)

// ---------------------------------------------------------------------------
// Transpose fp32 src[R][C] -> bf16 dst[C][R]  (R, C multiples of 32)
// ---------------------------------------------------------------------------
__global__ __launch_bounds__(256) void transpose_f32_to_bf16(
    const float* __restrict__ src, bf16_t* __restrict__ dst, int R, int C) {
  __shared__ bf16_t tile[32][33];
  const int c0 = blockIdx.x * 32, r0 = blockIdx.y * 32;
  const int tr = threadIdx.x >> 5;   // 0..7
  const int tc = threadIdx.x & 31;   // 0..31
#pragma unroll
  for (int i = 0; i < 32; i += 8)
    tile[tr + i][tc] = (bf16_t)src[(size_t)(r0 + tr + i) * C + (c0 + tc)];
  __syncthreads();
#pragma unroll
  for (int i = 0; i < 32; i += 8)
    dst[(size_t)(c0 + tr + i) * R + (r0 + tc)] = tile[tc][tr + i];
}

// ---------------------------------------------------------------------------
// GEMM  out = A[M][K] * BT[N][K]^T + bias[N]   (bf16 MFMA, fp32 acc)
// AF32:  A is fp32 global (converted to bf16 during LDS staging);
//        else A is bf16 workspace.
// QKV=true:  scatter bf16 into q [B*H][T][64], k [B*H][T][64], vt [B*H][64][T]
// QKV=false: write fp32 out[M][N].
// Block tile 128x128, 256 threads (4 waves, each 64x64 via 4x4 MFMA accs).
// ---------------------------------------------------------------------------
template <bool QKV, bool AF32>
__global__ __launch_bounds__(256) void gemm_bt(
    const void* __restrict__ Av, const bf16_t* __restrict__ BT,
    const float* __restrict__ bias,
    bf16_t* __restrict__ o0, bf16_t* __restrict__ o1, bf16_t* __restrict__ o2,
    float* __restrict__ of, int M, int N, int K) {
  constexpr int BM = 128, BN = 128, BK = 32, LDK = BK + 8;  // pad 40
  __shared__ __align__(16) bf16_t As[BM][LDK];
  __shared__ __align__(16) bf16_t Bs[BN][LDK];

  const int tid = threadIdx.x;
  const int wave = tid >> 6, lane = tid & 63;
  const int wr = wave >> 1, wc = wave & 1;
  const int quad = lane >> 4, l16 = lane & 15;
  const int mt = blockIdx.y, nt = blockIdx.x;

  const int srow = tid >> 1;        // 0..127
  const int scol = (tid & 1) << 4;  // 0 / 16
  const size_t a_off = (size_t)(mt * BM + srow) * K + scol;
  const bf16_t* Bg = BT + (size_t)(nt * BN + srow) * K + scol;

  f32x4 acc[4][4] = {};

  for (int k0 = 0; k0 < K; k0 += BK) {
    if (AF32) {
      const float* Ag = (const float*)Av + a_off + k0;
      const float4 a0 = *(const float4*)(Ag);
      const float4 a1 = *(const float4*)(Ag + 4);
      const float4 a2 = *(const float4*)(Ag + 8);
      const float4 a3 = *(const float4*)(Ag + 12);
      bf16x8 v0 = {(bf16_t)a0.x, (bf16_t)a0.y, (bf16_t)a0.z, (bf16_t)a0.w,
                   (bf16_t)a1.x, (bf16_t)a1.y, (bf16_t)a1.z, (bf16_t)a1.w};
      bf16x8 v1 = {(bf16_t)a2.x, (bf16_t)a2.y, (bf16_t)a2.z, (bf16_t)a2.w,
                   (bf16_t)a3.x, (bf16_t)a3.y, (bf16_t)a3.z, (bf16_t)a3.w};
      *(bf16x8*)(&As[srow][scol])     = v0;
      *(bf16x8*)(&As[srow][scol + 8]) = v1;
    } else {
      const bf16_t* Ag = (const bf16_t*)Av + a_off + k0;
      *(float4*)(&As[srow][scol])     = *(const float4*)(Ag);
      *(float4*)(&As[srow][scol + 8]) = *(const float4*)(Ag + 8);
    }
    *(float4*)(&Bs[srow][scol])     = *(const float4*)(Bg + k0);
    *(float4*)(&Bs[srow][scol + 8]) = *(const float4*)(Bg + k0 + 8);
    __syncthreads();

    bf16x8 af[4], bfr[4];
#pragma unroll
    for (int mi = 0; mi < 4; ++mi)
      af[mi] = *(const bf16x8*)(&As[wr * 64 + mi * 16 + l16][quad * 8]);
#pragma unroll
    for (int ni = 0; ni < 4; ++ni)
      bfr[ni] = *(const bf16x8*)(&Bs[wc * 64 + ni * 16 + l16][quad * 8]);
#pragma unroll
    for (int mi = 0; mi < 4; ++mi)
#pragma unroll
      for (int ni = 0; ni < 4; ++ni)
        acc[mi][ni] = MFMA16(af[mi], bfr[ni], acc[mi][ni]);
    __syncthreads();
  }

  // Epilogue. C/D layout: col = l16 (n), row = quad*4 + r (m).
  const int m_base = mt * BM + wr * 64;
  const int n_base = nt * BN + wc * 64;
#pragma unroll
  for (int ni = 0; ni < 4; ++ni) {
    const int n = n_base + ni * 16 + l16;
    const float bv = bias[n];
    int which = 0, h = 0, d = 0;
    if (QKV) {
      which = n / 768;
      const int c = n - which * 768;
      h = c >> 6;
      d = c & 63;
    }
#pragma unroll
    for (int mi = 0; mi < 4; ++mi) {
#pragma unroll
      for (int r = 0; r < 4; ++r) {
        const int m = m_base + mi * 16 + quad * 4 + r;
        const float val = acc[mi][ni][r] + bv;
        if (QKV) {
          const bf16_t bw = (bf16_t)val;
          const int b = m >> 10, t = m & 1023;
          const size_t bh = (size_t)(b * 12 + h);
          if (which == 0)
            o0[(bh * 1024 + t) * 64 + d] = bw;
          else if (which == 1)
            o1[(bh * 1024 + t) * 64 + d] = bw;
          else
            o2[(bh * 64 + d) * 1024 + t] = bw;
        } else {
          of[(size_t)m * N + n] = val;
        }
      }
    }
  }
}

// ---------------------------------------------------------------------------
// Causal flash attention.
// Q,K: [B*H][1024][64]; VT: [B*H][64][1024]; Y: [B][1024][768] (heads merged)
// Block = (qt, h, b): 64 q-rows, 4 waves x 16 rows. K-tiles of 64.
// ---------------------------------------------------------------------------
__global__ __launch_bounds__(256) void attn_fwd(
    const bf16_t* __restrict__ Q, const bf16_t* __restrict__ Kg,
    const bf16_t* __restrict__ VT, bf16_t* __restrict__ Y) {
  constexpr int LDA = 72;
  __shared__ __align__(16) bf16_t Ks[64][LDA];
  __shared__ __align__(16) bf16_t Vs[64][LDA];      // Vs[d][kpos]
  __shared__ __align__(16) bf16_t Ps[4][16][LDA];   // per-wave P tile

  const int tid = threadIdx.x;
  const int w = tid >> 6, lane = tid & 63;
  const int quad = lane >> 4, l16 = lane & 15;
  const int qt = blockIdx.x, h = blockIdx.y, b = blockIdx.z;
  const size_t bh = (size_t)(b * 12 + h);
  const bf16_t* Qbh = Q + bh * 1024 * 64;
  const bf16_t* Kbh = Kg + bh * 1024 * 64;
  const bf16_t* VTbh = VT + bh * 64 * 1024;

  // Preload Q A-fragments: A[m=l16][k=quad*8+j], k over hd=64 (2 steps)
  const int qrow = qt * 64 + w * 16 + l16;
  bf16x8 qf[2];
  qf[0] = *(const bf16x8*)(Qbh + (size_t)qrow * 64 + quad * 8);
  qf[1] = *(const bf16x8*)(Qbh + (size_t)qrow * 64 + 32 + quad * 8);

  float m_r[4], l_r[4];
  f32x4 o[4] = {};
#pragma unroll
  for (int r = 0; r < 4; ++r) { m_r[r] = -INFINITY; l_r[r] = 0.f; }

  const int srow = tid >> 2;        // 0..63
  const int scol = (tid & 3) << 4;  // 0,16,32,48

  for (int kt = 0; kt <= qt; ++kt) {
    const bf16_t* kg = Kbh + (size_t)(kt * 64 + srow) * 64 + scol;
    *(float4*)(&Ks[srow][scol])     = *(const float4*)(kg);
    *(float4*)(&Ks[srow][scol + 8]) = *(const float4*)(kg + 8);
    const bf16_t* vg = VTbh + (size_t)srow * 1024 + kt * 64 + scol;
    *(float4*)(&Vs[srow][scol])     = *(const float4*)(vg);
    *(float4*)(&Vs[srow][scol + 8]) = *(const float4*)(vg + 8);
    __syncthreads();

    // S = Q * K^T : per wave 16(q) x 64(k)
    f32x4 s[4];
#pragma unroll
    for (int ni = 0; ni < 4; ++ni) {
      bf16x8 kf0 = *(const bf16x8*)(&Ks[ni * 16 + l16][quad * 8]);
      bf16x8 kf1 = *(const bf16x8*)(&Ks[ni * 16 + l16][32 + quad * 8]);
      f32x4 t = {};
      t = MFMA16(qf[0], kf0, t);
      t = MFMA16(qf[1], kf1, t);
      s[ni] = t;
    }
    // scale (1/sqrt(64) = 0.125 exact) + causal mask on diagonal tile
#pragma unroll
    for (int ni = 0; ni < 4; ++ni) {
#pragma unroll
      for (int r = 0; r < 4; ++r) {
        float v = s[ni][r] * 0.125f;
        if (kt == qt) {
          const int kp = ni * 16 + l16;
          const int qr = w * 16 + quad * 4 + r;
          if (kp > qr) v = -INFINITY;
        }
        s[ni][r] = v;
      }
    }
    // row max across 4 in-lane cols + 16 lanes
    float alpha[4];
#pragma unroll
    for (int r = 0; r < 4; ++r) {
      float v = fmaxf(fmaxf(s[0][r], s[1][r]), fmaxf(s[2][r], s[3][r]));
      v = fmaxf(v, __shfl_xor(v, 1));
      v = fmaxf(v, __shfl_xor(v, 2));
      v = fmaxf(v, __shfl_xor(v, 4));
      v = fmaxf(v, __shfl_xor(v, 8));
      const float mn = fmaxf(m_r[r], v);
      alpha[r] = expf(m_r[r] - mn);
      m_r[r] = mn;
    }
    // P = exp(s - m) -> LDS (C-layout -> A-layout round trip), row sums
    float rs[4] = {0.f, 0.f, 0.f, 0.f};
#pragma unroll
    for (int ni = 0; ni < 4; ++ni) {
#pragma unroll
      for (int r = 0; r < 4; ++r) {
        const float p = expf(s[ni][r] - m_r[r]);
        rs[r] += p;
        Ps[w][quad * 4 + r][ni * 16 + l16] = (bf16_t)p;
      }
    }
#pragma unroll
    for (int r = 0; r < 4; ++r) {
      float v = rs[r];
      v += __shfl_xor(v, 1);
      v += __shfl_xor(v, 2);
      v += __shfl_xor(v, 4);
      v += __shfl_xor(v, 8);
      l_r[r] = l_r[r] * alpha[r] + v;
      o[0][r] *= alpha[r];
      o[1][r] *= alpha[r];
      o[2][r] *= alpha[r];
      o[3][r] *= alpha[r];
    }
    __syncthreads();  // Ps writes drained before A-frag reads

    // O += P * V : A[m=q=l16][k=kpos], B[n=d=l16][k=kpos] from Vs[d][kpos]
    bf16x8 pf0 = *(const bf16x8*)(&Ps[w][l16][quad * 8]);
    bf16x8 pf1 = *(const bf16x8*)(&Ps[w][l16][32 + quad * 8]);
#pragma unroll
    for (int nd = 0; nd < 4; ++nd) {
      bf16x8 vf0 = *(const bf16x8*)(&Vs[nd * 16 + l16][quad * 8]);
      bf16x8 vf1 = *(const bf16x8*)(&Vs[nd * 16 + l16][32 + quad * 8]);
      o[nd] = MFMA16(pf0, vf0, o[nd]);
      o[nd] = MFMA16(pf1, vf1, o[nd]);
    }
    __syncthreads();  // Ks/Vs consumed before next staging
  }

  // Y[b][t][h*64 + d] = O / l  (bf16 workspace feeding proj GEMM)
#pragma unroll
  for (int r = 0; r < 4; ++r) {
    const float inv = 1.0f / l_r[r];
    const int t = qt * 64 + w * 16 + quad * 4 + r;
    bf16_t* yrow = Y + ((size_t)b * 1024 + t) * 768 + h * 64;
#pragma unroll
    for (int nd = 0; nd < 4; ++nd)
      yrow[nd * 16 + l16] = (bf16_t)(o[nd][r] * inv);
  }
}

// ---------------------------------------------------------------------------
extern "C" void kernel_launch(void* const* d_in, const int* in_sizes, int n_in,
                              void* d_out, int out_size, void* d_ws,
                              size_t ws_size, hipStream_t stream) {
  const float* x      = (const float*)d_in[0];
  const float* W_attn = (const float*)d_in[1];
  const float* b_attn = (const float*)d_in[2];
  const float* W_proj = (const float*)d_in[3];
  const float* b_proj = (const float*)d_in[4];
  float* out = (float*)d_out;   // fp32 output per reference dtype

  const size_t HEADS = 96;  // B*H = 8*12
  bf16_t* wta = (bf16_t*)d_ws;                  // [2304][768]
  bf16_t* wtp = wta + (size_t)2304 * 768;       // [768][768]
  bf16_t* qw  = wtp + (size_t)768 * 768;        // [96][1024][64]
  bf16_t* kw  = qw + HEADS * 1024 * 64;         // [96][1024][64]
  bf16_t* vtw = kw + HEADS * 1024 * 64;         // [96][64][1024]
  bf16_t* yw  = vtw + HEADS * 1024 * 64;        // [8192][768]

  transpose_f32_to_bf16<<<dim3(2304 / 32, 768 / 32), 256, 0, stream>>>(
      W_attn, wta, 768, 2304);
  transpose_f32_to_bf16<<<dim3(768 / 32, 768 / 32), 256, 0, stream>>>(
      W_proj, wtp, 768, 768);
  gemm_bt<true, true><<<dim3(2304 / 128, 8192 / 128), 256, 0, stream>>>(
      x, wta, b_attn, qw, kw, vtw, nullptr, 8192, 2304, 768);
  attn_fwd<<<dim3(16, 12, 8), 256, 0, stream>>>(qw, kw, vtw, yw);
  gemm_bt<false, false><<<dim3(768 / 128, 8192 / 128), 256, 0, stream>>>(
      yw, wtp, b_proj, nullptr, nullptr, nullptr, out, 8192, 768, 768);
}

// Round 4
// 252.328 us; speedup vs baseline: 1.2373x; 1.2373x over previous
//
#include <hip/hip_runtime.h>
#include <hip/hip_bf16.h>
#include <cmath>

typedef __bf16 bf16_t;
typedef __bf16 bf16x8 __attribute__((ext_vector_type(8)));
typedef float f32x4 __attribute__((ext_vector_type(4)));

#define MFMA16(A, B, C) __builtin_amdgcn_mfma_f32_16x16x32_bf16(A, B, C, 0, 0, 0)

// ---------------------------------------------------------------------------
// Transpose fp32 src[R][C] -> bf16 dst[C][R]  (R, C multiples of 32)
// ---------------------------------------------------------------------------
__global__ __launch_bounds__(256) void transpose_f32_to_bf16(
    const float* __restrict__ src, bf16_t* __restrict__ dst, int R, int C) {
  __shared__ bf16_t tile[32][33];
  const int c0 = blockIdx.x * 32, r0 = blockIdx.y * 32;
  const int tr = threadIdx.x >> 5;   // 0..7
  const int tc = threadIdx.x & 31;   // 0..31
#pragma unroll
  for (int i = 0; i < 32; i += 8)
    tile[tr + i][tc] = (bf16_t)src[(size_t)(r0 + tr + i) * C + (c0 + tc)];
  __syncthreads();
#pragma unroll
  for (int i = 0; i < 32; i += 8)
    dst[(size_t)(c0 + tr + i) * R + (r0 + tc)] = tile[tc][tr + i];
}

// ---------------------------------------------------------------------------
// GEMM  out = A[M][K] * BT[N][K]^T + bias[N]   (bf16 MFMA, fp32 acc)
// AF32:  A is fp32 global (converted to bf16 during LDS staging);
//        else A is bf16 workspace.
// QKV=true:  scatter bf16 into q [B*H][T][64], k [B*H][T][64], vt [B*H][64][T]
// QKV=false: write fp32 out[M][N].
// Block tile 128x128, 256 threads (4 waves, each 64x64 via 4x4 MFMA accs).
// ---------------------------------------------------------------------------
template <bool QKV, bool AF32>
__global__ __launch_bounds__(256) void gemm_bt(
    const void* __restrict__ Av, const bf16_t* __restrict__ BT,
    const float* __restrict__ bias,
    bf16_t* __restrict__ o0, bf16_t* __restrict__ o1, bf16_t* __restrict__ o2,
    float* __restrict__ of, int M, int N, int K) {
  constexpr int BM = 128, BN = 128, BK = 32, LDK = BK + 8;  // pad 40
  __shared__ __align__(16) bf16_t As[BM][LDK];
  __shared__ __align__(16) bf16_t Bs[BN][LDK];

  const int tid = threadIdx.x;
  const int wave = tid >> 6, lane = tid & 63;
  const int wr = wave >> 1, wc = wave & 1;
  const int quad = lane >> 4, l16 = lane & 15;
  const int mt = blockIdx.y, nt = blockIdx.x;

  const int srow = tid >> 1;        // 0..127
  const int scol = (tid & 1) << 4;  // 0 / 16
  const size_t a_off = (size_t)(mt * BM + srow) * K + scol;
  const bf16_t* Bg = BT + (size_t)(nt * BN + srow) * K + scol;

  f32x4 acc[4][4] = {};

  for (int k0 = 0; k0 < K; k0 += BK) {
    if (AF32) {
      const float* Ag = (const float*)Av + a_off + k0;
      const float4 a0 = *(const float4*)(Ag);
      const float4 a1 = *(const float4*)(Ag + 4);
      const float4 a2 = *(const float4*)(Ag + 8);
      const float4 a3 = *(const float4*)(Ag + 12);
      bf16x8 v0 = {(bf16_t)a0.x, (bf16_t)a0.y, (bf16_t)a0.z, (bf16_t)a0.w,
                   (bf16_t)a1.x, (bf16_t)a1.y, (bf16_t)a1.z, (bf16_t)a1.w};
      bf16x8 v1 = {(bf16_t)a2.x, (bf16_t)a2.y, (bf16_t)a2.z, (bf16_t)a2.w,
                   (bf16_t)a3.x, (bf16_t)a3.y, (bf16_t)a3.z, (bf16_t)a3.w};
      *(bf16x8*)(&As[srow][scol])     = v0;
      *(bf16x8*)(&As[srow][scol + 8]) = v1;
    } else {
      const bf16_t* Ag = (const bf16_t*)Av + a_off + k0;
      *(float4*)(&As[srow][scol])     = *(const float4*)(Ag);
      *(float4*)(&As[srow][scol + 8]) = *(const float4*)(Ag + 8);
    }
    *(float4*)(&Bs[srow][scol])     = *(const float4*)(Bg + k0);
    *(float4*)(&Bs[srow][scol + 8]) = *(const float4*)(Bg + k0 + 8);
    __syncthreads();

    bf16x8 af[4], bfr[4];
#pragma unroll
    for (int mi = 0; mi < 4; ++mi)
      af[mi] = *(const bf16x8*)(&As[wr * 64 + mi * 16 + l16][quad * 8]);
#pragma unroll
    for (int ni = 0; ni < 4; ++ni)
      bfr[ni] = *(const bf16x8*)(&Bs[wc * 64 + ni * 16 + l16][quad * 8]);
#pragma unroll
    for (int mi = 0; mi < 4; ++mi)
#pragma unroll
      for (int ni = 0; ni < 4; ++ni)
        acc[mi][ni] = MFMA16(af[mi], bfr[ni], acc[mi][ni]);
    __syncthreads();
  }

  // Epilogue. C/D layout: col = l16 (n), row = quad*4 + r (m).
  const int m_base = mt * BM + wr * 64;
  const int n_base = nt * BN + wc * 64;
#pragma unroll
  for (int ni = 0; ni < 4; ++ni) {
    const int n = n_base + ni * 16 + l16;
    const float bv = bias[n];
    int which = 0, h = 0, d = 0;
    if (QKV) {
      which = n / 768;
      const int c = n - which * 768;
      h = c >> 6;
      d = c & 63;
    }
#pragma unroll
    for (int mi = 0; mi < 4; ++mi) {
#pragma unroll
      for (int r = 0; r < 4; ++r) {
        const int m = m_base + mi * 16 + quad * 4 + r;
        const float val = acc[mi][ni][r] + bv;
        if (QKV) {
          const bf16_t bw = (bf16_t)val;
          const int b = m >> 10, t = m & 1023;
          const size_t bh = (size_t)(b * 12 + h);
          if (which == 0)
            o0[(bh * 1024 + t) * 64 + d] = bw;
          else if (which == 1)
            o1[(bh * 1024 + t) * 64 + d] = bw;
          else
            o2[(bh * 64 + d) * 1024 + t] = bw;
        } else {
          of[(size_t)m * N + n] = val;
        }
      }
    }
  }
}

// ---------------------------------------------------------------------------
// Causal flash attention.
// Q,K: [B*H][1024][64]; VT: [B*H][64][1024]; Y: [B][1024][768] (heads merged)
// Block = (pair, h, b). Each block does q-tiles {15-pair, pair}: uniform 17
// k-tile iterations per block -> no load-imbalance tail. 4 waves x 16 q-rows.
// Softmax in log2 domain (exp2f, scale folded). Row-sum l via ones-column
// MFMA accumulator (same alpha recurrence as O columns).
// ---------------------------------------------------------------------------
__global__ __launch_bounds__(256) void attn_fwd(
    const bf16_t* __restrict__ Q, const bf16_t* __restrict__ Kg,
    const bf16_t* __restrict__ VT, bf16_t* __restrict__ Y) {
  constexpr int LDA = 72;
  __shared__ __align__(16) bf16_t Ks[64][LDA];
  __shared__ __align__(16) bf16_t Vs[64][LDA];      // Vs[d][kpos]
  __shared__ __align__(16) bf16_t Ps[4][16][LDA];   // per-wave P tile

  const int tid = threadIdx.x;
  const int w = tid >> 6, lane = tid & 63;
  const int quad = lane >> 4, l16 = lane & 15;
  const int pair = blockIdx.x, h = blockIdx.y, b = blockIdx.z;
  const size_t bh = (size_t)(b * 12 + h);
  const bf16_t* Qbh = Q + bh * 1024 * 64;
  const bf16_t* Kbh = Kg + bh * 1024 * 64;
  const bf16_t* VTbh = VT + bh * 64 * 1024;

  const int srow = tid >> 2;        // 0..63
  const int scol = (tid & 3) << 4;  // 0,16,32,48
  constexpr float SC = 0.18033688011112042f;  // log2(e) / sqrt(64)

  const bf16_t one_b = (bf16_t)1.0f;
  const bf16x8 ones = {one_b, one_b, one_b, one_b,
                       one_b, one_b, one_b, one_b};

  for (int phase = 0; phase < 2; ++phase) {
    const int qt = phase ? pair : (15 - pair);  // big tile first

    // Q A-fragments: A[m=l16][k=quad*8+j], k over hd=64 (2 chunks)
    const int qrow = qt * 64 + w * 16 + l16;
    bf16x8 qf0 = *(const bf16x8*)(Qbh + (size_t)qrow * 64 + quad * 8);
    bf16x8 qf1 = *(const bf16x8*)(Qbh + (size_t)qrow * 64 + 32 + quad * 8);

    float m_r[4];
    f32x4 o[5] = {};  // o[0..3]: V columns; o[4]: row-sum (l) via ones-MFMA
#pragma unroll
    for (int r = 0; r < 4; ++r) m_r[r] = -INFINITY;

    for (int kt = 0; kt <= qt; ++kt) {
      const bf16_t* kg = Kbh + (size_t)(kt * 64 + srow) * 64 + scol;
      *(float4*)(&Ks[srow][scol])     = *(const float4*)(kg);
      *(float4*)(&Ks[srow][scol + 8]) = *(const float4*)(kg + 8);
      const bf16_t* vg = VTbh + (size_t)srow * 1024 + kt * 64 + scol;
      *(float4*)(&Vs[srow][scol])     = *(const float4*)(vg);
      *(float4*)(&Vs[srow][scol + 8]) = *(const float4*)(vg + 8);
      __syncthreads();

      // S = Q * K^T : per wave 16(q) x 64(k)
      f32x4 s[4];
#pragma unroll
      for (int ni = 0; ni < 4; ++ni) {
        bf16x8 kf0 = *(const bf16x8*)(&Ks[ni * 16 + l16][quad * 8]);
        bf16x8 kf1 = *(const bf16x8*)(&Ks[ni * 16 + l16][32 + quad * 8]);
        f32x4 t = {};
        t = MFMA16(qf0, kf0, t);
        t = MFMA16(qf1, kf1, t);
        s[ni] = t;
      }
      // scale into log2 domain; causal mask on diagonal tile only
      if (kt == qt) {
#pragma unroll
        for (int ni = 0; ni < 4; ++ni)
#pragma unroll
          for (int r = 0; r < 4; ++r) {
            const int kp = ni * 16 + l16;
            const int qr = w * 16 + quad * 4 + r;
            s[ni][r] = (kp > qr) ? -INFINITY : s[ni][r] * SC;
          }
      } else {
#pragma unroll
        for (int ni = 0; ni < 4; ++ni)
#pragma unroll
          for (int r = 0; r < 4; ++r) s[ni][r] *= SC;
      }
      // row max (4 in-lane cols + 16 lanes), alpha = 2^(m_old - m_new)
      float alpha[4];
#pragma unroll
      for (int r = 0; r < 4; ++r) {
        float v = fmaxf(fmaxf(s[0][r], s[1][r]), fmaxf(s[2][r], s[3][r]));
        v = fmaxf(v, __shfl_xor(v, 1));
        v = fmaxf(v, __shfl_xor(v, 2));
        v = fmaxf(v, __shfl_xor(v, 4));
        v = fmaxf(v, __shfl_xor(v, 8));
        const float mn = fmaxf(m_r[r], v);
        alpha[r] = exp2f(m_r[r] - mn);
        m_r[r] = mn;
      }
      // P = 2^(s-m) -> Ps (C-layout -> A-layout round trip; per-wave region,
      // intra-wave lgkmcnt dependency only -> no barrier needed)
#pragma unroll
      for (int ni = 0; ni < 4; ++ni)
#pragma unroll
        for (int r = 0; r < 4; ++r)
          Ps[w][quad * 4 + r][ni * 16 + l16] =
              (bf16_t)exp2f(s[ni][r] - m_r[r]);
      // rescale accumulators (incl. l-column)
#pragma unroll
      for (int nd = 0; nd < 5; ++nd)
#pragma unroll
        for (int r = 0; r < 4; ++r) o[nd][r] *= alpha[r];

      // O += P * V ; l += P * 1
      bf16x8 pf0 = *(const bf16x8*)(&Ps[w][l16][quad * 8]);
      bf16x8 pf1 = *(const bf16x8*)(&Ps[w][l16][32 + quad * 8]);
#pragma unroll
      for (int nd = 0; nd < 4; ++nd) {
        bf16x8 vf0 = *(const bf16x8*)(&Vs[nd * 16 + l16][quad * 8]);
        bf16x8 vf1 = *(const bf16x8*)(&Vs[nd * 16 + l16][32 + quad * 8]);
        o[nd] = MFMA16(pf0, vf0, o[nd]);
        o[nd] = MFMA16(pf1, vf1, o[nd]);
      }
      o[4] = MFMA16(pf0, ones, o[4]);
      o[4] = MFMA16(pf1, ones, o[4]);
      __syncthreads();  // Ks/Vs consumed before next staging
    }

    // Y[b][t][h*64 + d] = O / l
#pragma unroll
    for (int r = 0; r < 4; ++r) {
      const float inv = 1.0f / o[4][r];
      const int t = qt * 64 + w * 16 + quad * 4 + r;
      bf16_t* yrow = Y + ((size_t)b * 1024 + t) * 768 + h * 64;
#pragma unroll
      for (int nd = 0; nd < 4; ++nd)
        yrow[nd * 16 + l16] = (bf16_t)(o[nd][r] * inv);
    }
  }
}

// ---------------------------------------------------------------------------
extern "C" void kernel_launch(void* const* d_in, const int* in_sizes, int n_in,
                              void* d_out, int out_size, void* d_ws,
                              size_t ws_size, hipStream_t stream) {
  const float* x      = (const float*)d_in[0];
  const float* W_attn = (const float*)d_in[1];
  const float* b_attn = (const float*)d_in[2];
  const float* W_proj = (const float*)d_in[3];
  const float* b_proj = (const float*)d_in[4];
  float* out = (float*)d_out;   // fp32 output per reference dtype

  const size_t HEADS = 96;  // B*H = 8*12
  bf16_t* wta = (bf16_t*)d_ws;                  // [2304][768]
  bf16_t* wtp = wta + (size_t)2304 * 768;       // [768][768]
  bf16_t* qw  = wtp + (size_t)768 * 768;        // [96][1024][64]
  bf16_t* kw  = qw + HEADS * 1024 * 64;         // [96][1024][64]
  bf16_t* vtw = kw + HEADS * 1024 * 64;         // [96][64][1024]
  bf16_t* yw  = vtw + HEADS * 1024 * 64;        // [8192][768]

  transpose_f32_to_bf16<<<dim3(2304 / 32, 768 / 32), 256, 0, stream>>>(
      W_attn, wta, 768, 2304);
  transpose_f32_to_bf16<<<dim3(768 / 32, 768 / 32), 256, 0, stream>>>(
      W_proj, wtp, 768, 768);
  gemm_bt<true, true><<<dim3(2304 / 128, 8192 / 128), 256, 0, stream>>>(
      x, wta, b_attn, qw, kw, vtw, nullptr, 8192, 2304, 768);
  attn_fwd<<<dim3(8, 12, 8), 256, 0, stream>>>(qw, kw, vtw, yw);
  gemm_bt<false, false><<<dim3(768 / 128, 8192 / 128), 256, 0, stream>>>(
      yw, wtp, b_proj, nullptr, nullptr, nullptr, out, 8192, 768, 768);
}

// Round 5
// 238.820 us; speedup vs baseline: 1.3073x; 1.0566x over previous
//
#include <hip/hip_runtime.h>
#include <hip/hip_bf16.h>
#include <cmath>

typedef __bf16 bf16_t;
typedef __bf16 bf16x8 __attribute__((ext_vector_type(8)));
typedef float f32x4 __attribute__((ext_vector_type(4)));

#define MFMA16(A, B, C) __builtin_amdgcn_mfma_f32_16x16x32_bf16(A, B, C, 0, 0, 0)

// Async global->LDS DMA, 16 B per lane. LDS dest = wave-uniform base + lane*16.
#define GLOAD_LDS16(g, l)                                                      \
  __builtin_amdgcn_global_load_lds(                                            \
      (const __attribute__((address_space(1))) void*)(g),                      \
      (__attribute__((address_space(3))) void*)(l), 16, 0, 0)

// ---------------------------------------------------------------------------
// fp32 -> bf16 elementwise (x pre-convert), 8 elems/thread
// ---------------------------------------------------------------------------
__global__ __launch_bounds__(256) void f32_to_bf16(
    const float* __restrict__ src, bf16_t* __restrict__ dst) {
  const size_t i = (size_t)blockIdx.x * 256 + threadIdx.x;
  const float4 a0 = ((const float4*)src)[i * 2];
  const float4 a1 = ((const float4*)src)[i * 2 + 1];
  bf16x8 v = {(bf16_t)a0.x, (bf16_t)a0.y, (bf16_t)a0.z, (bf16_t)a0.w,
              (bf16_t)a1.x, (bf16_t)a1.y, (bf16_t)a1.z, (bf16_t)a1.w};
  ((bf16x8*)dst)[i] = v;
}

// ---------------------------------------------------------------------------
// Transpose fp32 src[R][C] -> bf16 dst[C][R]  (R, C multiples of 32)
// ---------------------------------------------------------------------------
__global__ __launch_bounds__(256) void transpose_f32_to_bf16(
    const float* __restrict__ src, bf16_t* __restrict__ dst, int R, int C) {
  __shared__ bf16_t tile[32][33];
  const int c0 = blockIdx.x * 32, r0 = blockIdx.y * 32;
  const int tr = threadIdx.x >> 5;   // 0..7
  const int tc = threadIdx.x & 31;   // 0..31
#pragma unroll
  for (int i = 0; i < 32; i += 8)
    tile[tr + i][tc] = (bf16_t)src[(size_t)(r0 + tr + i) * C + (c0 + tc)];
  __syncthreads();
#pragma unroll
  for (int i = 0; i < 32; i += 8)
    dst[(size_t)(c0 + tr + i) * R + (r0 + tc)] = tile[tc][tr + i];
}

// ---------------------------------------------------------------------------
// GEMM  out = A[M][K] * BT[N][K]^T + bias[N]   (bf16 in, fp32 acc)
// m97 structure: global_load_lds width-16 staging into unpadded [128][32]
// LDS tiles (lane i -> row i/4, 16B chunk i%4; b128 frag reads hit all 32
// banks uniformly). 128x128 tile, 4 waves, 4x4 16x16x32 accs each.
// QKV=true:  scatter bf16 into q [B*H][T][64], k [B*H][T][64], vt [B*H][64][T]
// QKV=false: write fp32 of[M][N].
// ---------------------------------------------------------------------------
template <bool QKV>
__global__ __launch_bounds__(256) void gemm_bt(
    const bf16_t* __restrict__ A, const bf16_t* __restrict__ BT,
    const float* __restrict__ bias,
    bf16_t* __restrict__ o0, bf16_t* __restrict__ o1, bf16_t* __restrict__ o2,
    float* __restrict__ of, int M, int N, int K) {
  constexpr int BM = 128, BN = 128, BK = 32;
  __shared__ __align__(16) bf16_t As[BM][BK];
  __shared__ __align__(16) bf16_t Bs[BN][BK];

  const int tid = threadIdx.x;
  const int wave = tid >> 6, lane = tid & 63;
  const int wr = wave >> 1, wc = wave & 1;
  const int quad = lane >> 4, l16 = lane & 15;
  const int mt = blockIdx.y, nt = blockIdx.x;

  // staging map: chunk = wave*2 + j covers rows [chunk*16, chunk*16+16)
  const int ar = lane >> 2;          // row within chunk
  const int ac = (lane & 3) << 3;    // bf16 col: 0,8,16,24
  const bf16_t* Ag0 = A + (size_t)(mt * BM + wave * 32 + ar) * K + ac;
  const bf16_t* Ag1 = Ag0 + (size_t)16 * K;
  const bf16_t* Bg0 = BT + (size_t)(nt * BN + wave * 32 + ar) * K + ac;
  const bf16_t* Bg1 = Bg0 + (size_t)16 * K;
  bf16_t* AsL0 = &As[wave * 32][0];
  bf16_t* AsL1 = &As[wave * 32 + 16][0];
  bf16_t* BsL0 = &Bs[wave * 32][0];
  bf16_t* BsL1 = &Bs[wave * 32 + 16][0];

  f32x4 acc[4][4] = {};

  for (int k0 = 0; k0 < K; k0 += BK) {
    GLOAD_LDS16(Ag0 + k0, AsL0);
    GLOAD_LDS16(Ag1 + k0, AsL1);
    GLOAD_LDS16(Bg0 + k0, BsL0);
    GLOAD_LDS16(Bg1 + k0, BsL1);
    __syncthreads();  // vmcnt(0) drain before barrier covers the DMA

    bf16x8 af[4], bfr[4];
#pragma unroll
    for (int mi = 0; mi < 4; ++mi)
      af[mi] = *(const bf16x8*)(&As[wr * 64 + mi * 16 + l16][quad * 8]);
#pragma unroll
    for (int ni = 0; ni < 4; ++ni)
      bfr[ni] = *(const bf16x8*)(&Bs[wc * 64 + ni * 16 + l16][quad * 8]);
#pragma unroll
    for (int mi = 0; mi < 4; ++mi)
#pragma unroll
      for (int ni = 0; ni < 4; ++ni)
        acc[mi][ni] = MFMA16(af[mi], bfr[ni], acc[mi][ni]);
    __syncthreads();
  }

  // Epilogue. C/D layout: col = l16 (n), row = quad*4 + r (m).
  const int m_base = mt * BM + wr * 64;
  const int n_base = nt * BN + wc * 64;
#pragma unroll
  for (int ni = 0; ni < 4; ++ni) {
    const int n = n_base + ni * 16 + l16;
    const float bv = bias[n];
    int which = 0, h = 0, d = 0;
    if (QKV) {
      which = n / 768;
      const int c = n - which * 768;
      h = c >> 6;
      d = c & 63;
    }
#pragma unroll
    for (int mi = 0; mi < 4; ++mi) {
#pragma unroll
      for (int r = 0; r < 4; ++r) {
        const int m = m_base + mi * 16 + quad * 4 + r;
        const float val = acc[mi][ni][r] + bv;
        if (QKV) {
          const bf16_t bw = (bf16_t)val;
          const int b = m >> 10, t = m & 1023;
          const size_t bh = (size_t)(b * 12 + h);
          if (which == 0)
            o0[(bh * 1024 + t) * 64 + d] = bw;
          else if (which == 1)
            o1[(bh * 1024 + t) * 64 + d] = bw;
          else
            o2[(bh * 64 + d) * 1024 + t] = bw;
        } else {
          of[(size_t)m * N + n] = val;
        }
      }
    }
  }
}

// ---------------------------------------------------------------------------
// Causal flash attention.
// Q,K: [B*H][1024][64]; VT: [B*H][64][1024]; Y: [B][1024][768] (heads merged)
// Block = (pair, h, b); q-tiles {15-pair, pair} -> uniform 17 k-tiles/block.
// Softmax in log2 domain; row-sum l via ones-column MFMA.
// ---------------------------------------------------------------------------
__global__ __launch_bounds__(256) void attn_fwd(
    const bf16_t* __restrict__ Q, const bf16_t* __restrict__ Kg,
    const bf16_t* __restrict__ VT, bf16_t* __restrict__ Y) {
  constexpr int LDA = 72;
  __shared__ __align__(16) bf16_t Ks[64][LDA];
  __shared__ __align__(16) bf16_t Vs[64][LDA];      // Vs[d][kpos]
  __shared__ __align__(16) bf16_t Ps[4][16][LDA];   // per-wave P tile

  const int tid = threadIdx.x;
  const int w = tid >> 6, lane = tid & 63;
  const int quad = lane >> 4, l16 = lane & 15;
  const int pair = blockIdx.x, h = blockIdx.y, b = blockIdx.z;
  const size_t bh = (size_t)(b * 12 + h);
  const bf16_t* Qbh = Q + bh * 1024 * 64;
  const bf16_t* Kbh = Kg + bh * 1024 * 64;
  const bf16_t* VTbh = VT + bh * 64 * 1024;

  const int srow = tid >> 2;        // 0..63
  const int scol = (tid & 3) << 4;  // 0,16,32,48
  constexpr float SC = 0.18033688011112042f;  // log2(e) / sqrt(64)

  const bf16_t one_b = (bf16_t)1.0f;
  const bf16x8 ones = {one_b, one_b, one_b, one_b,
                       one_b, one_b, one_b, one_b};

  for (int phase = 0; phase < 2; ++phase) {
    const int qt = phase ? pair : (15 - pair);  // big tile first

    const int qrow = qt * 64 + w * 16 + l16;
    bf16x8 qf0 = *(const bf16x8*)(Qbh + (size_t)qrow * 64 + quad * 8);
    bf16x8 qf1 = *(const bf16x8*)(Qbh + (size_t)qrow * 64 + 32 + quad * 8);

    float m_r[4];
    f32x4 o[5] = {};  // o[0..3]: V columns; o[4]: row-sum (l)
#pragma unroll
    for (int r = 0; r < 4; ++r) m_r[r] = -INFINITY;

    for (int kt = 0; kt <= qt; ++kt) {
      const bf16_t* kg = Kbh + (size_t)(kt * 64 + srow) * 64 + scol;
      *(float4*)(&Ks[srow][scol])     = *(const float4*)(kg);
      *(float4*)(&Ks[srow][scol + 8]) = *(const float4*)(kg + 8);
      const bf16_t* vg = VTbh + (size_t)srow * 1024 + kt * 64 + scol;
      *(float4*)(&Vs[srow][scol])     = *(const float4*)(vg);
      *(float4*)(&Vs[srow][scol + 8]) = *(const float4*)(vg + 8);
      __syncthreads();

      // S = Q * K^T
      f32x4 s[4];
#pragma unroll
      for (int ni = 0; ni < 4; ++ni) {
        bf16x8 kf0 = *(const bf16x8*)(&Ks[ni * 16 + l16][quad * 8]);
        bf16x8 kf1 = *(const bf16x8*)(&Ks[ni * 16 + l16][32 + quad * 8]);
        f32x4 t = {};
        t = MFMA16(qf0, kf0, t);
        t = MFMA16(qf1, kf1, t);
        s[ni] = t;
      }
      if (kt == qt) {
#pragma unroll
        for (int ni = 0; ni < 4; ++ni)
#pragma unroll
          for (int r = 0; r < 4; ++r) {
            const int kp = ni * 16 + l16;
            const int qr = w * 16 + quad * 4 + r;
            s[ni][r] = (kp > qr) ? -INFINITY : s[ni][r] * SC;
          }
      } else {
#pragma unroll
        for (int ni = 0; ni < 4; ++ni)
#pragma unroll
          for (int r = 0; r < 4; ++r) s[ni][r] *= SC;
      }
      float alpha[4];
#pragma unroll
      for (int r = 0; r < 4; ++r) {
        float v = fmaxf(fmaxf(s[0][r], s[1][r]), fmaxf(s[2][r], s[3][r]));
        v = fmaxf(v, __shfl_xor(v, 1));
        v = fmaxf(v, __shfl_xor(v, 2));
        v = fmaxf(v, __shfl_xor(v, 4));
        v = fmaxf(v, __shfl_xor(v, 8));
        const float mn = fmaxf(m_r[r], v);
        alpha[r] = exp2f(m_r[r] - mn);
        m_r[r] = mn;
      }
      // P -> Ps (per-wave region; intra-wave dependency only, no barrier)
#pragma unroll
      for (int ni = 0; ni < 4; ++ni)
#pragma unroll
        for (int r = 0; r < 4; ++r)
          Ps[w][quad * 4 + r][ni * 16 + l16] =
              (bf16_t)exp2f(s[ni][r] - m_r[r]);
#pragma unroll
      for (int nd = 0; nd < 5; ++nd)
#pragma unroll
        for (int r = 0; r < 4; ++r) o[nd][r] *= alpha[r];

      bf16x8 pf0 = *(const bf16x8*)(&Ps[w][l16][quad * 8]);
      bf16x8 pf1 = *(const bf16x8*)(&Ps[w][l16][32 + quad * 8]);
#pragma unroll
      for (int nd = 0; nd < 4; ++nd) {
        bf16x8 vf0 = *(const bf16x8*)(&Vs[nd * 16 + l16][quad * 8]);
        bf16x8 vf1 = *(const bf16x8*)(&Vs[nd * 16 + l16][32 + quad * 8]);
        o[nd] = MFMA16(pf0, vf0, o[nd]);
        o[nd] = MFMA16(pf1, vf1, o[nd]);
      }
      o[4] = MFMA16(pf0, ones, o[4]);
      o[4] = MFMA16(pf1, ones, o[4]);
      __syncthreads();  // Ks/Vs consumed before next staging
    }

#pragma unroll
    for (int r = 0; r < 4; ++r) {
      const float inv = 1.0f / o[4][r];
      const int t = qt * 64 + w * 16 + quad * 4 + r;
      bf16_t* yrow = Y + ((size_t)b * 1024 + t) * 768 + h * 64;
#pragma unroll
      for (int nd = 0; nd < 4; ++nd)
        yrow[nd * 16 + l16] = (bf16_t)(o[nd][r] * inv);
    }
  }
}

// ---------------------------------------------------------------------------
extern "C" void kernel_launch(void* const* d_in, const int* in_sizes, int n_in,
                              void* d_out, int out_size, void* d_ws,
                              size_t ws_size, hipStream_t stream) {
  const float* x      = (const float*)d_in[0];
  const float* W_attn = (const float*)d_in[1];
  const float* b_attn = (const float*)d_in[2];
  const float* W_proj = (const float*)d_in[3];
  const float* b_proj = (const float*)d_in[4];
  float* out = (float*)d_out;   // fp32 output per reference dtype

  const size_t HEADS = 96;  // B*H = 8*12
  bf16_t* wta = (bf16_t*)d_ws;                  // [2304][768]
  bf16_t* wtp = wta + (size_t)2304 * 768;       // [768][768]
  bf16_t* qw  = wtp + (size_t)768 * 768;        // [96][1024][64]
  bf16_t* kw  = qw + HEADS * 1024 * 64;         // [96][1024][64]
  bf16_t* vtw = kw + HEADS * 1024 * 64;         // [96][64][1024]
  bf16_t* yw  = vtw + HEADS * 1024 * 64;        // [8192][768]
  bf16_t* xb  = yw + (size_t)8192 * 768;        // [8192][768] bf16 x

  f32_to_bf16<<<dim3(8192 * 768 / (256 * 8)), 256, 0, stream>>>(x, xb);
  transpose_f32_to_bf16<<<dim3(2304 / 32, 768 / 32), 256, 0, stream>>>(
      W_attn, wta, 768, 2304);
  transpose_f32_to_bf16<<<dim3(768 / 32, 768 / 32), 256, 0, stream>>>(
      W_proj, wtp, 768, 768);
  gemm_bt<true><<<dim3(2304 / 128, 8192 / 128), 256, 0, stream>>>(
      xb, wta, b_attn, qw, kw, vtw, nullptr, 8192, 2304, 768);
  attn_fwd<<<dim3(8, 12, 8), 256, 0, stream>>>(qw, kw, vtw, yw);
  gemm_bt<false><<<dim3(768 / 128, 8192 / 128), 256, 0, stream>>>(
      yw, wtp, b_proj, nullptr, nullptr, nullptr, out, 8192, 768, 768);
}

// Round 6
// 235.102 us; speedup vs baseline: 1.3279x; 1.0158x over previous
//
#include <hip/hip_runtime.h>
#include <hip/hip_bf16.h>
#include <cmath>

typedef __bf16 bf16_t;
typedef __bf16 bf16x8 __attribute__((ext_vector_type(8)));
typedef float f32x4 __attribute__((ext_vector_type(4)));

#define MFMA16(A, B, C) __builtin_amdgcn_mfma_f32_16x16x32_bf16(A, B, C, 0, 0, 0)

// Async global->LDS DMA, 16 B per lane. LDS dest = wave-uniform base + lane*16.
#define GLOAD_LDS16(g, l)                                                      \
  __builtin_amdgcn_global_load_lds(                                            \
      (const __attribute__((address_space(1))) void*)(g),                      \
      (__attribute__((address_space(3))) void*)(l), 16, 0, 0)

// ---------------------------------------------------------------------------
// fp32 -> bf16 elementwise (x pre-convert), 8 elems/thread
// ---------------------------------------------------------------------------
__global__ __launch_bounds__(256) void f32_to_bf16(
    const float* __restrict__ src, bf16_t* __restrict__ dst) {
  const size_t i = (size_t)blockIdx.x * 256 + threadIdx.x;
  const float4 a0 = ((const float4*)src)[i * 2];
  const float4 a1 = ((const float4*)src)[i * 2 + 1];
  bf16x8 v = {(bf16_t)a0.x, (bf16_t)a0.y, (bf16_t)a0.z, (bf16_t)a0.w,
              (bf16_t)a1.x, (bf16_t)a1.y, (bf16_t)a1.z, (bf16_t)a1.w};
  ((bf16x8*)dst)[i] = v;
}

// ---------------------------------------------------------------------------
// Transpose fp32 src[R][C] -> bf16 dst[C][R]  (R, C multiples of 32)
// ---------------------------------------------------------------------------
__global__ __launch_bounds__(256) void transpose_f32_to_bf16(
    const float* __restrict__ src, bf16_t* __restrict__ dst, int R, int C) {
  __shared__ bf16_t tile[32][33];
  const int c0 = blockIdx.x * 32, r0 = blockIdx.y * 32;
  const int tr = threadIdx.x >> 5;   // 0..7
  const int tc = threadIdx.x & 31;   // 0..31
#pragma unroll
  for (int i = 0; i < 32; i += 8)
    tile[tr + i][tc] = (bf16_t)src[(size_t)(r0 + tr + i) * C + (c0 + tc)];
  __syncthreads();
#pragma unroll
  for (int i = 0; i < 32; i += 8)
    dst[(size_t)(c0 + tr + i) * R + (r0 + tc)] = tile[tc][tr + i];
}

// ---------------------------------------------------------------------------
// GEMM  out = A[M][K] * BT[N][K]^T + bias[N]   (bf16 in, fp32 acc)
// Pipelined m97 structure: double-buffered [128][32] LDS tiles, ONE barrier
// per K-iter, DMA for tile k+1 issued right after the barrier (a full
// compute phase of latency hiding), compute on tile k. K/BK must be even.
// QKV=true:  scatter bf16 into q [B*H][T][64], k [B*H][T][64], vt [B*H][64][T]
// QKV=false: write fp32 of[M][N].
// ---------------------------------------------------------------------------
template <bool QKV>
__global__ __launch_bounds__(256) void gemm_bt(
    const bf16_t* __restrict__ A, const bf16_t* __restrict__ BT,
    const float* __restrict__ bias,
    bf16_t* __restrict__ o0, bf16_t* __restrict__ o1, bf16_t* __restrict__ o2,
    float* __restrict__ of, int M, int N, int K) {
  constexpr int BM = 128, BN = 128, BK = 32;
  __shared__ __align__(16) bf16_t As[2][BM][BK];  // 16 KB
  __shared__ __align__(16) bf16_t Bs[2][BN][BK];  // 16 KB

  const int tid = threadIdx.x;
  const int wave = tid >> 6, lane = tid & 63;
  const int wr = wave >> 1, wc = wave & 1;
  const int quad = lane >> 4, l16 = lane & 15;
  const int mt = blockIdx.y, nt = blockIdx.x;

  // staging map: lane i -> row i/4, 16B chunk i%4 within a 16-row block
  const int ar = lane >> 2;          // row within chunk
  const int ac = (lane & 3) << 3;    // bf16 col: 0,8,16,24
  const bf16_t* Ag0 = A + (size_t)(mt * BM + wave * 32 + ar) * K + ac;
  const bf16_t* Ag1 = Ag0 + (size_t)16 * K;
  const bf16_t* Bg0 = BT + (size_t)(nt * BN + wave * 32 + ar) * K + ac;
  const bf16_t* Bg1 = Bg0 + (size_t)16 * K;

  f32x4 acc[4][4] = {};

  auto stage = [&](int k0, int buf) {
    GLOAD_LDS16(Ag0 + k0, &As[buf][wave * 32][0]);
    GLOAD_LDS16(Ag1 + k0, &As[buf][wave * 32 + 16][0]);
    GLOAD_LDS16(Bg0 + k0, &Bs[buf][wave * 32][0]);
    GLOAD_LDS16(Bg1 + k0, &Bs[buf][wave * 32 + 16][0]);
  };
  auto compute = [&](int buf) {
    bf16x8 af[4], bfr[4];
#pragma unroll
    for (int mi = 0; mi < 4; ++mi)
      af[mi] = *(const bf16x8*)(&As[buf][wr * 64 + mi * 16 + l16][quad * 8]);
#pragma unroll
    for (int ni = 0; ni < 4; ++ni)
      bfr[ni] = *(const bf16x8*)(&Bs[buf][wc * 64 + ni * 16 + l16][quad * 8]);
#pragma unroll
    for (int mi = 0; mi < 4; ++mi)
#pragma unroll
      for (int ni = 0; ni < 4; ++ni)
        acc[mi][ni] = MFMA16(af[mi], bfr[ni], acc[mi][ni]);
  };

  const int NIT = K / BK;  // 24 for K=768 (even)
  stage(0, 0);
  for (int k = 0; k + 2 < NIT; k += 2) {
    __syncthreads();           // tile k   landed; buf1 free
    stage((k + 1) * BK, 1);    // prefetch tile k+1
    compute(0);                // compute tile k
    __syncthreads();           // tile k+1 landed; buf0 free
    stage((k + 2) * BK, 0);    // prefetch tile k+2
    compute(1);                // compute tile k+1
  }
  __syncthreads();
  stage((NIT - 1) * BK, 1);
  compute(0);                  // tile NIT-2
  __syncthreads();
  compute(1);                  // tile NIT-1

  // Epilogue. C/D layout: col = l16 (n), row = quad*4 + r (m).
  const int m_base = mt * BM + wr * 64;
  const int n_base = nt * BN + wc * 64;
#pragma unroll
  for (int ni = 0; ni < 4; ++ni) {
    const int n = n_base + ni * 16 + l16;
    const float bv = bias[n];
    int which = 0, h = 0, d = 0;
    if (QKV) {
      which = n / 768;
      const int c = n - which * 768;
      h = c >> 6;
      d = c & 63;
    }
#pragma unroll
    for (int mi = 0; mi < 4; ++mi) {
#pragma unroll
      for (int r = 0; r < 4; ++r) {
        const int m = m_base + mi * 16 + quad * 4 + r;
        const float val = acc[mi][ni][r] + bv;
        if (QKV) {
          const bf16_t bw = (bf16_t)val;
          const int b = m >> 10, t = m & 1023;
          const size_t bh = (size_t)(b * 12 + h);
          if (which == 0)
            o0[(bh * 1024 + t) * 64 + d] = bw;
          else if (which == 1)
            o1[(bh * 1024 + t) * 64 + d] = bw;
          else
            o2[(bh * 64 + d) * 1024 + t] = bw;
        } else {
          of[(size_t)m * N + n] = val;
        }
      }
    }
  }
}

// ---------------------------------------------------------------------------
// Causal flash attention.
// Q,K: [B*H][1024][64]; VT: [B*H][64][1024]; Y: [B][1024][768] (heads merged)
// Block = (pair, h, b); q-tiles {15-pair, pair} -> uniform 17 k-tiles/block.
// Softmax in log2 domain; row-sum l via ones-column MFMA.
// ---------------------------------------------------------------------------
__global__ __launch_bounds__(256) void attn_fwd(
    const bf16_t* __restrict__ Q, const bf16_t* __restrict__ Kg,
    const bf16_t* __restrict__ VT, bf16_t* __restrict__ Y) {
  constexpr int LDA = 72;
  __shared__ __align__(16) bf16_t Ks[64][LDA];
  __shared__ __align__(16) bf16_t Vs[64][LDA];      // Vs[d][kpos]
  __shared__ __align__(16) bf16_t Ps[4][16][LDA];   // per-wave P tile

  const int tid = threadIdx.x;
  const int w = tid >> 6, lane = tid & 63;
  const int quad = lane >> 4, l16 = lane & 15;
  const int pair = blockIdx.x, h = blockIdx.y, b = blockIdx.z;
  const size_t bh = (size_t)(b * 12 + h);
  const bf16_t* Qbh = Q + bh * 1024 * 64;
  const bf16_t* Kbh = Kg + bh * 1024 * 64;
  const bf16_t* VTbh = VT + bh * 64 * 1024;

  const int srow = tid >> 2;        // 0..63
  const int scol = (tid & 3) << 4;  // 0,16,32,48
  constexpr float SC = 0.18033688011112042f;  // log2(e) / sqrt(64)

  const bf16_t one_b = (bf16_t)1.0f;
  const bf16x8 ones = {one_b, one_b, one_b, one_b,
                       one_b, one_b, one_b, one_b};

  for (int phase = 0; phase < 2; ++phase) {
    const int qt = phase ? pair : (15 - pair);  // big tile first

    const int qrow = qt * 64 + w * 16 + l16;
    bf16x8 qf0 = *(const bf16x8*)(Qbh + (size_t)qrow * 64 + quad * 8);
    bf16x8 qf1 = *(const bf16x8*)(Qbh + (size_t)qrow * 64 + 32 + quad * 8);

    float m_r[4];
    f32x4 o[5] = {};  // o[0..3]: V columns; o[4]: row-sum (l)
#pragma unroll
    for (int r = 0; r < 4; ++r) m_r[r] = -INFINITY;

    for (int kt = 0; kt <= qt; ++kt) {
      const bf16_t* kg = Kbh + (size_t)(kt * 64 + srow) * 64 + scol;
      *(float4*)(&Ks[srow][scol])     = *(const float4*)(kg);
      *(float4*)(&Ks[srow][scol + 8]) = *(const float4*)(kg + 8);
      const bf16_t* vg = VTbh + (size_t)srow * 1024 + kt * 64 + scol;
      *(float4*)(&Vs[srow][scol])     = *(const float4*)(vg);
      *(float4*)(&Vs[srow][scol + 8]) = *(const float4*)(vg + 8);
      __syncthreads();

      // S = Q * K^T
      f32x4 s[4];
#pragma unroll
      for (int ni = 0; ni < 4; ++ni) {
        bf16x8 kf0 = *(const bf16x8*)(&Ks[ni * 16 + l16][quad * 8]);
        bf16x8 kf1 = *(const bf16x8*)(&Ks[ni * 16 + l16][32 + quad * 8]);
        f32x4 t = {};
        t = MFMA16(qf0, kf0, t);
        t = MFMA16(qf1, kf1, t);
        s[ni] = t;
      }
      if (kt == qt) {
#pragma unroll
        for (int ni = 0; ni < 4; ++ni)
#pragma unroll
          for (int r = 0; r < 4; ++r) {
            const int kp = ni * 16 + l16;
            const int qr = w * 16 + quad * 4 + r;
            s[ni][r] = (kp > qr) ? -INFINITY : s[ni][r] * SC;
          }
      } else {
#pragma unroll
        for (int ni = 0; ni < 4; ++ni)
#pragma unroll
          for (int r = 0; r < 4; ++r) s[ni][r] *= SC;
      }
      float alpha[4];
#pragma unroll
      for (int r = 0; r < 4; ++r) {
        float v = fmaxf(fmaxf(s[0][r], s[1][r]), fmaxf(s[2][r], s[3][r]));
        v = fmaxf(v, __shfl_xor(v, 1));
        v = fmaxf(v, __shfl_xor(v, 2));
        v = fmaxf(v, __shfl_xor(v, 4));
        v = fmaxf(v, __shfl_xor(v, 8));
        const float mn = fmaxf(m_r[r], v);
        alpha[r] = exp2f(m_r[r] - mn);
        m_r[r] = mn;
      }
      // P -> Ps (per-wave region; intra-wave dependency only, no barrier)
#pragma unroll
      for (int ni = 0; ni < 4; ++ni)
#pragma unroll
        for (int r = 0; r < 4; ++r)
          Ps[w][quad * 4 + r][ni * 16 + l16] =
              (bf16_t)exp2f(s[ni][r] - m_r[r]);
#pragma unroll
      for (int nd = 0; nd < 5; ++nd)
#pragma unroll
        for (int r = 0; r < 4; ++r) o[nd][r] *= alpha[r];

      bf16x8 pf0 = *(const bf16x8*)(&Ps[w][l16][quad * 8]);
      bf16x8 pf1 = *(const bf16x8*)(&Ps[w][l16][32 + quad * 8]);
#pragma unroll
      for (int nd = 0; nd < 4; ++nd) {
        bf16x8 vf0 = *(const bf16x8*)(&Vs[nd * 16 + l16][quad * 8]);
        bf16x8 vf1 = *(const bf16x8*)(&Vs[nd * 16 + l16][32 + quad * 8]);
        o[nd] = MFMA16(pf0, vf0, o[nd]);
        o[nd] = MFMA16(pf1, vf1, o[nd]);
      }
      o[4] = MFMA16(pf0, ones, o[4]);
      o[4] = MFMA16(pf1, ones, o[4]);
      __syncthreads();  // Ks/Vs consumed before next staging
    }

#pragma unroll
    for (int r = 0; r < 4; ++r) {
      const float inv = 1.0f / o[4][r];
      const int t = qt * 64 + w * 16 + quad * 4 + r;
      bf16_t* yrow = Y + ((size_t)b * 1024 + t) * 768 + h * 64;
#pragma unroll
      for (int nd = 0; nd < 4; ++nd)
        yrow[nd * 16 + l16] = (bf16_t)(o[nd][r] * inv);
    }
  }
}

// ---------------------------------------------------------------------------
extern "C" void kernel_launch(void* const* d_in, const int* in_sizes, int n_in,
                              void* d_out, int out_size, void* d_ws,
                              size_t ws_size, hipStream_t stream) {
  const float* x      = (const float*)d_in[0];
  const float* W_attn = (const float*)d_in[1];
  const float* b_attn = (const float*)d_in[2];
  const float* W_proj = (const float*)d_in[3];
  const float* b_proj = (const float*)d_in[4];
  float* out = (float*)d_out;   // fp32 output per reference dtype

  const size_t HEADS = 96;  // B*H = 8*12
  bf16_t* wta = (bf16_t*)d_ws;                  // [2304][768]
  bf16_t* wtp = wta + (size_t)2304 * 768;       // [768][768]
  bf16_t* qw  = wtp + (size_t)768 * 768;        // [96][1024][64]
  bf16_t* kw  = qw + HEADS * 1024 * 64;         // [96][1024][64]
  bf16_t* vtw = kw + HEADS * 1024 * 64;         // [96][64][1024]
  bf16_t* yw  = vtw + HEADS * 1024 * 64;        // [8192][768]
  bf16_t* xb  = yw + (size_t)8192 * 768;        // [8192][768] bf16 x

  f32_to_bf16<<<dim3(8192 * 768 / (256 * 8)), 256, 0, stream>>>(x, xb);
  transpose_f32_to_bf16<<<dim3(2304 / 32, 768 / 32), 256, 0, stream>>>(
      W_attn, wta, 768, 2304);
  transpose_f32_to_bf16<<<dim3(768 / 32, 768 / 32), 256, 0, stream>>>(
      W_proj, wtp, 768, 768);
  gemm_bt<true><<<dim3(2304 / 128, 8192 / 128), 256, 0, stream>>>(
      xb, wta, b_attn, qw, kw, vtw, nullptr, 8192, 2304, 768);
  attn_fwd<<<dim3(8, 12, 8), 256, 0, stream>>>(qw, kw, vtw, yw);
  gemm_bt<false><<<dim3(768 / 128, 8192 / 128), 256, 0, stream>>>(
      yw, wtp, b_proj, nullptr, nullptr, nullptr, out, 8192, 768, 768);
}